// Round 8
// baseline (440.150 us; speedup 1.0000x reference)
//
#include <hip/hip_runtime.h>

#define N_NODES 100000
#define P_PAIRS 3200000
#define IN_F    19
#define OUT_F   64
#define BN_EPS  1e-5f
#define SLOPE   0.01f
#define BSHIFT  8       // 256 keys per bucket
#define BUCKETS 391     // ceil(N_NODES / 256)
#define CAP     9000    // staging capacity per bucket (mean 8184, sd ~90)
#define CHUNK_P 6400    // pairs per bucket1 block (P / 6400 = 500 blocks)
#define B1_NIT  13      // ceil(CHUNK_P / 512) register-stash iters
#define B1_BLOCKS 500   // bucket1 blocks
#define K1_BLOCKS 500   // gemm blocks appended to the same launch
#define NCH     2       // channel chunks
#define CH_F    32      // channels per chunk (64 B rows = exactly one cache line)
#define MF_GRID 1024    // fused mlp+final grid (= 4 blocks/CU x 256 CUs, all resident)
#define MF_TOTW (MF_GRID * 4)

typedef __attribute__((ext_vector_type(8))) unsigned short u16x8;
typedef __attribute__((ext_vector_type(8))) short bf16x8;
typedef __attribute__((ext_vector_type(4))) float f32x4;

__device__ __forceinline__ float bf2f(unsigned short h) {
    return __uint_as_float(((unsigned)h) << 16);
}
__device__ __forceinline__ unsigned short f2bf(float f) {
    unsigned u = __float_as_uint(f);
    return (unsigned short)((u + 0x7FFF + ((u >> 16) & 1)) >> 16);  // RNE
}

// ---------------------------------------------------------------------------
// wave-level inclusive scan helper (64-lane shfl)
// ---------------------------------------------------------------------------
__device__ __forceinline__ int wave_incl_scan(int v, int lane) {
    #pragma unroll
    for (int off = 1; off < 64; off <<= 1) {
        int u = __shfl_up(v, off, 64);
        if (lane >= off) v += u;
    }
    return v;
}

// ---------------------------------------------------------------------------
// K2: merged launch — blocks [0,500): bucket phase 1 (both sides, wave-shfl
// scans, register-stashed pairs); blocks [500,1000): input GEMM
// xw = x @ W_conv -> bf16 chunk-major [2][N][32]. bucket1 is ~13% VALUBusy,
// so the GEMM blocks ride its idle issue slots (removes a serial stage).
// ---------------------------------------------------------------------------
__global__ __launch_bounds__(512) void k_b1_gemm(
    const int* __restrict__ ni, const int* __restrict__ ei,
    int* __restrict__ curE, int* __restrict__ curN,
    unsigned int* __restrict__ stageE, unsigned int* __restrict__ stageN,
    const float* __restrict__ x, const float* __restrict__ Wc,
    unsigned short* __restrict__ xwb)
{
    __shared__ int histE[BUCKETS], histN[BUCKETS];
    __shared__ int cE[BUCKETS], cN[BUCKETS];
    __shared__ int gbE[BUCKETS], gbN[BUCKETS];
    __shared__ int wsum[8], wexc[8];
    __shared__ unsigned int scrE[CHUNK_P], scrN[CHUNK_P];
    int t = threadIdx.x;
    int lane = t & 63;
    int wv = t >> 6;

    if (blockIdx.x >= B1_BLOCKS) {
        // ---- input GEMM branch ----
        float w[IN_F];
        #pragma unroll
        for (int k = 0; k < IN_F; ++k) w[k] = Wc[k * OUT_F + lane];
        size_t coff = (size_t)(lane >> 5) * (N_NODES * CH_F) + (lane & 31);
        int gw = ((blockIdx.x - B1_BLOCKS) * 512 + t) >> 6;   // 0..4000
        int nw = K1_BLOCKS * 8;
        for (int n = gw * 2; n < N_NODES; n += nw * 2) {      // N even
            const float* xr0 = x + (size_t)n * IN_F;
            const float* xr1 = xr0 + IN_F;
            float a0 = 0.f, a1 = 0.f;
            #pragma unroll
            for (int k = 0; k < IN_F; ++k) {
                a0 += xr0[k] * w[k];
                a1 += xr1[k] * w[k];
            }
            xwb[coff + (size_t)n * CH_F]       = f2bf(a0);
            xwb[coff + (size_t)(n + 1) * CH_F] = f2bf(a1);
        }
        return;
    }

    // ---- bucket1 branch ----
    for (int b = t; b < BUCKETS; b += 512) { histE[b] = 0; histN[b] = 0; }
    __syncthreads();
    int p0 = blockIdx.x * CHUNK_P;
    int nv[B1_NIT], ev[B1_NIT];
    #pragma unroll
    for (int r = 0; r < B1_NIT; ++r) {
        int i = t + (r << 9);
        if (i < CHUNK_P) {
            nv[r] = ni[p0 + i];
            ev[r] = ei[p0 + i];
            atomicAdd(&histE[ev[r] >> BSHIFT], 1);
            atomicAdd(&histN[nv[r] >> BSHIFT], 1);
        }
    }
    __syncthreads();
    // scan edge-side (wave shfl scan + 8-wave combine)
    {
        int c = (t < BUCKETS) ? histE[t] : 0;
        int incl = wave_incl_scan(c, lane);
        if (lane == 63) wsum[wv] = incl;
        __syncthreads();
        if (wv == 0 && lane < 8) {
            int x_ = wsum[lane];
            int xi = x_;
            #pragma unroll
            for (int off = 1; off < 8; off <<= 1) {
                int u = __shfl_up(xi, off, 8);
                if (lane >= off) xi += u;
            }
            wexc[lane] = xi - x_;          // exclusive across waves
        }
        __syncthreads();
        incl += wexc[wv];
        if (t < BUCKETS) {
            gbE[t] = (c > 0) ? atomicAdd(&curE[t], c) : 0;
            cE[t] = incl - c;              // exclusive local cursor
        }
    }
    __syncthreads();
    // scan node-side
    {
        int c = (t < BUCKETS) ? histN[t] : 0;
        int incl = wave_incl_scan(c, lane);
        if (lane == 63) wsum[wv] = incl;
        __syncthreads();
        if (wv == 0 && lane < 8) {
            int x_ = wsum[lane];
            int xi = x_;
            #pragma unroll
            for (int off = 1; off < 8; off <<= 1) {
                int u = __shfl_up(xi, off, 8);
                if (lane >= off) xi += u;
            }
            wexc[lane] = xi - x_;
        }
        __syncthreads();
        incl += wexc[wv];
        if (t < BUCKETS) {
            gbN[t] = (c > 0) ? atomicAdd(&curN[t], c) : 0;
            cN[t] = incl - c;
        }
    }
    __syncthreads();
    // pass 2: place packed entries at sorted LDS positions (from registers)
    #pragma unroll
    for (int r = 0; r < B1_NIT; ++r) {
        int i = t + (r << 9);
        if (i < CHUNK_P) {
            int n = nv[r];
            int e = ev[r];
            int pE = atomicAdd(&cE[e >> BSHIFT], 1);
            scrE[pE] = ((unsigned)(e & 255) << 17) | (unsigned)n;
            int pN = atomicAdd(&cN[n >> BSHIFT], 1);
            scrN[pN] = ((unsigned)(n & 255) << 17) | (unsigned)e;
        }
    }
    __syncthreads();
    // flush: 32 groups x 16 lanes stream whole bucket runs (full-line bursts)
    int grp = t >> 4, l16 = t & 15;
    for (int b = grp; b < BUCKETS; b += 32) {
        int c = histE[b];
        if (c > 0) {
            int ls = cE[b] - c;            // cE[b] is inclusive end now
            int gs = gbE[b];
            size_t sb = (size_t)b * CAP;
            for (int j = l16; j < c; j += 16)
                if (gs + j < CAP) stageE[sb + gs + j] = scrE[ls + j];
        }
        c = histN[b];
        if (c > 0) {
            int ls = cN[b] - c;
            int gs = gbN[b];
            size_t sb = (size_t)b * CAP;
            for (int j = l16; j < c; j += 16)
                if (gs + j < CAP) stageN[sb + gs + j] = scrN[ls + j];
        }
    }
}

// ---------------------------------------------------------------------------
// K4: bucket phase 2 — E and N merged (782 blocks). Inlined base (sum of
// cur[0..b)). Counting-sort into LDS scratch, then LINEAR COALESCED flush
// adj[sbase+i] = scr[i]  (fixed R6's 5.6x write amplification).
// ---------------------------------------------------------------------------
__global__ __launch_bounds__(512) void k_bucket2(
    const unsigned int* __restrict__ stageE, const unsigned int* __restrict__ stageN,
    const int* __restrict__ curE, const int* __restrict__ curN,
    int* __restrict__ adjE, int* __restrict__ adjN,
    int* __restrict__ offE, int* __restrict__ offN,
    int* __restrict__ lenE, int* __restrict__ lenN)
{
    __shared__ int cnt[256];
    __shared__ int pos[256];               // per-key placement cursor
    __shared__ int wsum[8], wexc[8];
    __shared__ int sbase;
    __shared__ int scr[CAP];               // sorted values (36 KB)
    int bb = blockIdx.x;
    int side = (bb >= BUCKETS);
    int b = side ? bb - BUCKETS : bb;
    const unsigned int* stage = side ? stageN : stageE;
    const int* cur = side ? curN : curE;
    int* adj  = side ? adjN : adjE;
    int* offK = side ? offN : offE;
    int* lenK = side ? lenN : lenE;

    int t = threadIdx.x;
    int lane = t & 63;
    int wv = t >> 6;
    if (t == 0) sbase = 0;
    if (t < 8) { wsum[t] = 0; wexc[t] = 0; }
    if (t < 256) cnt[t] = 0;
    __syncthreads();
    // base = sum cur[0..b) (L2-warm, <=391 ints)
    int partial = 0;
    for (int i = t; i < b; i += 512) partial += cur[i];
    #pragma unroll
    for (int m = 1; m < 64; m <<= 1) partial += __shfl_xor(partial, m, 64);
    if (lane == 0 && partial != 0) atomicAdd(&sbase, partial);
    // per-key histogram
    int m_ = cur[b]; if (m_ > CAP) m_ = CAP;
    size_t sg = (size_t)b * CAP;
    for (int i = t; i < m_; i += 512)
        atomicAdd(&cnt[stage[sg + i] >> 17], 1);
    __syncthreads();
    // 256-entry exclusive scan of cnt: 4 wave scans + combine
    {
        int c = (t < 256) ? cnt[t] : 0;
        int incl = 0;
        if (t < 256) {
            incl = wave_incl_scan(c, lane);
            if (lane == 63) wsum[wv] = incl;
        }
        __syncthreads();
        if (wv == 0 && lane < 8) {
            int x_ = wsum[lane];
            int xi = x_;
            #pragma unroll
            for (int off = 1; off < 8; off <<= 1) {
                int u = __shfl_up(xi, off, 8);
                if (lane >= off) xi += u;
            }
            wexc[lane] = xi - x_;
        }
        __syncthreads();
        if (t < 256) {
            int loff = incl + wexc[wv] - c;   // local offset within bucket
            int k = (b << BSHIFT) + t;
            if (k < N_NODES) { offK[k] = sbase + loff; lenK[k] = c; }
            pos[t] = loff;
        }
    }
    __syncthreads();
    // place into LDS scratch (sorted by key)
    for (int i = t; i < m_; i += 512) {
        unsigned v = stage[sg + i];
        int p = atomicAdd(&pos[v >> 17], 1);
        scr[p] = (int)(v & 0x1FFFF);
    }
    __syncthreads();
    // flush: fully coalesced linear stream (full-line writes)
    for (int i = t; i < m_; i += 512)
        adj[sbase + i] = scr[i];
}

// ---------------------------------------------------------------------------
// gather-accumulate over adj[s,e) with 4 independent chains
// ---------------------------------------------------------------------------
__device__ __forceinline__ void gather_range(
    const int* __restrict__ adj, const unsigned short* __restrict__ tin,
    int s, int e, int sub, int cg, float acc[8])
{
    int i = s + sub;
    for (; i + 12 < e; i += 16) {
        int i0 = __builtin_nontemporal_load(&adj[i]);
        int i1 = __builtin_nontemporal_load(&adj[i + 4]);
        int i2 = __builtin_nontemporal_load(&adj[i + 8]);
        int i3 = __builtin_nontemporal_load(&adj[i + 12]);
        u16x8 v0 = *(const u16x8*)(tin + (size_t)i0 * CH_F + cg * 8);
        u16x8 v1 = *(const u16x8*)(tin + (size_t)i1 * CH_F + cg * 8);
        u16x8 v2 = *(const u16x8*)(tin + (size_t)i2 * CH_F + cg * 8);
        u16x8 v3 = *(const u16x8*)(tin + (size_t)i3 * CH_F + cg * 8);
        #pragma unroll
        for (int j = 0; j < 8; ++j) acc[j] += bf2f(v0[j]);
        #pragma unroll
        for (int j = 0; j < 8; ++j) acc[j] += bf2f(v1[j]);
        #pragma unroll
        for (int j = 0; j < 8; ++j) acc[j] += bf2f(v2[j]);
        #pragma unroll
        for (int j = 0; j < 8; ++j) acc[j] += bf2f(v3[j]);
    }
    if (i + 4 < e) {
        int i0 = __builtin_nontemporal_load(&adj[i]);
        int i1 = __builtin_nontemporal_load(&adj[i + 4]);
        u16x8 v0 = *(const u16x8*)(tin + (size_t)i0 * CH_F + cg * 8);
        u16x8 v1 = *(const u16x8*)(tin + (size_t)i1 * CH_F + cg * 8);
        #pragma unroll
        for (int j = 0; j < 8; ++j) acc[j] += bf2f(v0[j]);
        #pragma unroll
        for (int j = 0; j < 8; ++j) acc[j] += bf2f(v1[j]);
        i += 8;
    }
    if (i < e) {
        int i0 = __builtin_nontemporal_load(&adj[i]);
        u16x8 v0 = *(const u16x8*)(tin + (size_t)i0 * CH_F + cg * 8);
        #pragma unroll
        for (int j = 0; j < 8; ++j) acc[j] += bf2f(v0[j]);
    }
}

// ---------------------------------------------------------------------------
// K5: fused hop (R4 form — measured-best; residency splits all lost).
// 64 B rows = one cache line per gather. chunk = b & 1 (XCD parity).
// ---------------------------------------------------------------------------
__global__ __launch_bounds__(256) void k_hop(
    const int* __restrict__ adj, const int* __restrict__ offK,
    const int* __restrict__ lenK, const unsigned short* __restrict__ tin_base,
    unsigned short* __restrict__ tout_base, const float* __restrict__ bcc)
{
    int b = blockIdx.x;                    // grid = 12500
    int chunk = b & 1;
    int sb = b >> 1;                       // 0..6249
    const unsigned short* tin = tin_base + (size_t)chunk * (N_NODES * CH_F);
    unsigned short* tout = tout_base + (size_t)chunk * (N_NODES * CH_F);

    int lane = threadIdx.x & 63;
    int wv = threadIdx.x >> 6;
    int es  = lane >> 4;                   // segment within wave
    int sub = (lane >> 2) & 3;             // row-slot within segment
    int cg  = lane & 3;                    // 16 B quarter within 64 B row
    int k = (sb * 4 + wv) * 4 + es;
    int len = lenK[k];
    int start = offK[k];

    float acc[8];
    #pragma unroll
    for (int j = 0; j < 8; ++j) acc[j] = 0.f;

    gather_range(adj, tin, start, start + len, sub, cg, acc);

    #pragma unroll
    for (int m = 4; m < 16; m <<= 1) {     // reduce over sub (lane bits 2..3)
        #pragma unroll
        for (int j = 0; j < 8; ++j) acc[j] += __shfl_xor(acc[j], m, 64);
    }
    if ((lane & 12) == 0) {                // sub == 0
        float sc = (len > 0) ? 1.f / (float)len : 0.f;
        u16x8 o;
        if (bcc) {
            #pragma unroll
            for (int j = 0; j < 8; ++j)
                o[j] = f2bf(acc[j] * sc + bcc[chunk * CH_F + cg * 8 + j]);
        } else {
            #pragma unroll
            for (int j = 0; j < 8; ++j) o[j] = f2bf(acc[j] * sc);
        }
        __builtin_nontemporal_store(o, (u16x8*)(tout + (size_t)k * CH_F + cg * 8));
    }
}

// ---------------------------------------------------------------------------
// K6: FUSED MLP + BN + residual + LeakyReLU. Phase 1: MFMA h-tiles -> LDS,
// BN partials -> bns (global atomics). Grid-wide spin barrier (all 1024
// blocks resident by construction: __launch_bounds__(256,4) = 4 blk/CU x
// 256 CUs = grid; LDS 33 KB <= 40 KB/block). Phase 2: normalize from LDS,
// add residual x@Wr, write out. Saves the 51 MB h round-trip + one launch.
// ---------------------------------------------------------------------------
__global__ __launch_bounds__(256, 4) void k_mlp_final(
    const unsigned short* __restrict__ cvb, const float* __restrict__ Wm,
    const float* __restrict__ bm, const float* __restrict__ x,
    const float* __restrict__ Wr, const float* __restrict__ br,
    const float* __restrict__ gamma, const float* __restrict__ beta,
    float* __restrict__ out, float* __restrict__ bns,
    unsigned int* __restrict__ ctr)
{
    __shared__ float red[128];             // [sum 64][sumsq 64]
    __shared__ float hl[4][2][16][64];     // per-wave h tiles (32 KB)
    if (threadIdx.x < 128) red[threadIdx.x] = 0.f;
    __syncthreads();

    int lane = threadIdx.x & 63;
    int wv = threadIdx.x >> 6;
    int q = lane >> 4;
    int c = lane & 15;
    const int NT = N_NODES / 16;
    int gw = (blockIdx.x * 256 + threadIdx.x) >> 6;   // 0..4095

    // ---- phase 1: h = cv @ Wm + bm -> LDS, BN partials ----
    {
        bf16x8 bf[4][2];
        #pragma unroll
        for (int tt = 0; tt < 4; ++tt)
            #pragma unroll
            for (int kh = 0; kh < 2; ++kh)
                #pragma unroll
                for (int j = 0; j < 8; ++j)
                    bf[tt][kh][j] = (short)f2bf(Wm[(kh * 32 + q * 8 + j) * OUT_F + tt * 16 + c]);
        float bmv[4];
        #pragma unroll
        for (int tt = 0; tt < 4; ++tt) bmv[tt] = bm[tt * 16 + c];

        float s[4], s2[4];
        #pragma unroll
        for (int tt = 0; tt < 4; ++tt) { s[tt] = 0.f; s2[tt] = 0.f; }

        #pragma unroll
        for (int slot = 0; slot < 2; ++slot) {
            int tile = gw + slot * MF_TOTW;
            if (tile < NT) {
                int r0 = tile * 16;
                size_t rowoff = (size_t)(r0 + c) * CH_F + q * 8;
                bf16x8 a0 = *(const bf16x8*)(cvb + rowoff);
                bf16x8 a1 = *(const bf16x8*)(cvb + (size_t)(N_NODES * CH_F) + rowoff);
                #pragma unroll
                for (int tt = 0; tt < 4; ++tt) {
                    f32x4 acc = {0.f, 0.f, 0.f, 0.f};
                    acc = __builtin_amdgcn_mfma_f32_16x16x32_bf16(a0, bf[tt][0], acc, 0, 0, 0);
                    acc = __builtin_amdgcn_mfma_f32_16x16x32_bf16(a1, bf[tt][1], acc, 0, 0, 0);
                    #pragma unroll
                    for (int r = 0; r < 4; ++r) {
                        float hv = acc[r] + bmv[tt];
                        hl[wv][slot][q * 4 + r][tt * 16 + c] = hv;
                        s[tt]  += hv;
                        s2[tt] += hv * hv;
                    }
                }
            }
        }
        #pragma unroll
        for (int tt = 0; tt < 4; ++tt) {
            #pragma unroll
            for (int m = 16; m < 64; m <<= 1) {
                s[tt]  += __shfl_xor(s[tt],  m, 64);
                s2[tt] += __shfl_xor(s2[tt], m, 64);
            }
        }
        if (lane < 16) {
            #pragma unroll
            for (int tt = 0; tt < 4; ++tt) {
                atomicAdd(&red[tt * 16 + lane], s[tt]);
                atomicAdd(&red[64 + tt * 16 + lane], s2[tt]);
            }
        }
        __syncthreads();
        if (threadIdx.x < 128) atomicAdd(&bns[threadIdx.x], red[threadIdx.x]);
    }

    // ---- grid-wide spin barrier (all blocks resident) ----
    __threadfence();
    __syncthreads();
    if (threadIdx.x == 0) {
        atomicAdd(ctr, 1u);
        while (__hip_atomic_load(ctr, __ATOMIC_ACQUIRE, __HIP_MEMORY_SCOPE_AGENT)
               < (unsigned)gridDim.x) {
            __builtin_amdgcn_s_sleep(2);
        }
    }
    __syncthreads();

    // ---- phase 2: normalize + LeakyReLU + residual + LeakyReLU ----
    const float inv_n = 1.f / (float)N_NODES;
    float mean = __hip_atomic_load(&bns[lane], __ATOMIC_RELAXED,
                                   __HIP_MEMORY_SCOPE_AGENT) * inv_n;
    float var  = __hip_atomic_load(&bns[64 + lane], __ATOMIC_RELAXED,
                                   __HIP_MEMORY_SCOPE_AGENT) * inv_n - mean * mean;
    float rstd = rsqrtf(var + BN_EPS);
    float g = gamma[lane], bt = beta[lane];
    float rb = br[lane];
    float w[IN_F];
    #pragma unroll
    for (int k = 0; k < IN_F; ++k) w[k] = Wr[k * OUT_F + lane];

    #pragma unroll
    for (int slot = 0; slot < 2; ++slot) {
        int tile = gw + slot * MF_TOTW;
        if (tile < NT) {
            int r0 = tile * 16;
            #pragma unroll 4
            for (int r = 0; r < 16; ++r) {
                float hv = hl[wv][slot][r][lane];
                float a = g * (hv - mean) * rstd + bt;
                a = (a >= 0.f) ? a : SLOPE * a;
                const float* xr = x + (size_t)(r0 + r) * IN_F;
                float res = rb;
                #pragma unroll
                for (int k = 0; k < IN_F; ++k) res += xr[k] * w[k];
                float y = a + res;
                out[(size_t)(r0 + r) * OUT_F + lane] = (y >= 0.f) ? y : SLOPE * y;
            }
        }
    }
}

// ---------------------------------------------------------------------------
extern "C" void kernel_launch(void* const* d_in, const int* in_sizes, int n_in,
                              void* d_out, int out_size, void* d_ws, size_t ws_size,
                              hipStream_t stream) {
    const float* x     = (const float*)d_in[0];
    const int*   hidx  = (const int*)d_in[1];
    const int*   ni    = hidx;               // row 0: node idx
    const int*   ei    = hidx + P_PAIRS;     // row 1: edge idx
    const float* Wc    = (const float*)d_in[2];
    const float* bc    = (const float*)d_in[3];
    const float* Wm    = (const float*)d_in[4];
    const float* bm    = (const float*)d_in[5];
    const float* gamma = (const float*)d_in[6];
    const float* beta  = (const float*)d_in[7];
    const float* Wr    = (const float*)d_in[8];
    const float* br    = (const float*)d_in[9];
    float* out = (float*)d_out;

    // --- ws (~94 MB of the 256 MB workspace), no aliasing:
    int* adjE = (int*)d_ws;                                  // P
    int* adjN = adjE + P_PAIRS;                              // P
    unsigned int* stageE = (unsigned int*)(adjN + P_PAIRS);  // BUCKETS*CAP
    unsigned int* stageN = stageE + (size_t)BUCKETS * CAP;   // BUCKETS*CAP
    unsigned short* xwb = (unsigned short*)(stageN + (size_t)BUCKETS * CAP); // [2][N][32]
    unsigned short* efb = xwb + (size_t)NCH * N_NODES * CH_F;
    unsigned short* cvb = efb + (size_t)NCH * N_NODES * CH_F;
    float* bns = (float*)(cvb + (size_t)NCH * N_NODES * CH_F); // 128 f
    unsigned int* ctr = (unsigned int*)(bns + 128);            // 1 u32 (+3 pad)
    int* curE  = (int*)(ctr + 4);
    int* curN  = curE + BUCKETS;
    int* offE  = curN + BUCKETS;
    int* lenE  = offE + N_NODES;
    int* offN  = lenE + N_NODES;
    int* lenN  = offN + N_NODES;

    // zero bns + ctr + curE + curN (contiguous)
    hipMemsetAsync(bns, 0, (128 + 4 + 2 * BUCKETS) * sizeof(int), stream);

    // bucket1 (blocks 0-499) + input GEMM (blocks 500-999) in one launch
    k_b1_gemm<<<B1_BLOCKS + K1_BLOCKS, 512, 0, stream>>>(
        ni, ei, curE, curN, stageE, stageN, x, Wc, xwb);

    k_bucket2<<<2 * BUCKETS, 512, 0, stream>>>(stageE, stageN, curE, curN,
                                               adjE, adjN, offE, offN,
                                               lenE, lenN);

    k_hop<<<12500, 256, 0, stream>>>(adjE, offE, lenE, xwb, efb, (const float*)nullptr);
    k_hop<<<12500, 256, 0, stream>>>(adjN, offN, lenN, efb, cvb, bc);

    k_mlp_final<<<MF_GRID, 256, 0, stream>>>(cvb, Wm, bm, x, Wr, br,
                                             gamma, beta, out, bns, ctr);
}

// Round 9
// 338.075 us; speedup vs baseline: 1.3019x; 1.3019x over previous
//
#include <hip/hip_runtime.h>

#define N_NODES 100000
#define P_PAIRS 3200000
#define IN_F    19
#define OUT_F   64
#define BN_EPS  1e-5f
#define SLOPE   0.01f
#define BSHIFT  8       // 256 keys per bucket
#define BUCKETS 391     // ceil(N_NODES / 256)
#define CAP     9000    // staging capacity per bucket (mean 8184, sd ~90)
#define CHUNK_P 6400    // pairs per bucket1 block (P / 6400 = 500 blocks)
#define B1_NIT  13      // ceil(CHUNK_P / 512) register-stash iters
#define B1_BLOCKS 500   // bucket1 blocks
#define K1_BLOCKS 500   // gemm blocks appended to the same launch
#define NCH     2       // channel chunks
#define CH_F    32      // channels per chunk (64 B rows = exactly one cache line)

typedef __attribute__((ext_vector_type(8))) unsigned short u16x8;
typedef __attribute__((ext_vector_type(8))) short bf16x8;
typedef __attribute__((ext_vector_type(4))) float f32x4;

__device__ __forceinline__ float bf2f(unsigned short h) {
    return __uint_as_float(((unsigned)h) << 16);
}
__device__ __forceinline__ unsigned short f2bf(float f) {
    unsigned u = __float_as_uint(f);
    return (unsigned short)((u + 0x7FFF + ((u >> 16) & 1)) >> 16);  // RNE
}

// ---------------------------------------------------------------------------
// wave-level inclusive scan helper (64-lane shfl)
// ---------------------------------------------------------------------------
__device__ __forceinline__ int wave_incl_scan(int v, int lane) {
    #pragma unroll
    for (int off = 1; off < 64; off <<= 1) {
        int u = __shfl_up(v, off, 64);
        if (lane >= off) v += u;
    }
    return v;
}

// ---------------------------------------------------------------------------
// K2: merged launch — blocks [0,500): bucket phase 1 (both sides, wave-shfl
// scans, register-stashed pairs); blocks [500,1000): input GEMM
// xw = x @ W_conv -> bf16 chunk-major [2][N][32]. bucket1 is ~13% VALUBusy,
// so the GEMM blocks ride its idle issue slots (removes a serial stage).
// ---------------------------------------------------------------------------
__global__ __launch_bounds__(512) void k_b1_gemm(
    const int* __restrict__ ni, const int* __restrict__ ei,
    int* __restrict__ curE, int* __restrict__ curN,
    unsigned int* __restrict__ stageE, unsigned int* __restrict__ stageN,
    const float* __restrict__ x, const float* __restrict__ Wc,
    unsigned short* __restrict__ xwb)
{
    __shared__ int histE[BUCKETS], histN[BUCKETS];
    __shared__ int cE[BUCKETS], cN[BUCKETS];
    __shared__ int gbE[BUCKETS], gbN[BUCKETS];
    __shared__ int wsum[8], wexc[8];
    __shared__ unsigned int scrE[CHUNK_P], scrN[CHUNK_P];
    int t = threadIdx.x;
    int lane = t & 63;
    int wv = t >> 6;

    if (blockIdx.x >= B1_BLOCKS) {
        // ---- input GEMM branch ----
        float w[IN_F];
        #pragma unroll
        for (int k = 0; k < IN_F; ++k) w[k] = Wc[k * OUT_F + lane];
        size_t coff = (size_t)(lane >> 5) * (N_NODES * CH_F) + (lane & 31);
        int gw = ((blockIdx.x - B1_BLOCKS) * 512 + t) >> 6;   // 0..4000
        int nw = K1_BLOCKS * 8;
        for (int n = gw * 2; n < N_NODES; n += nw * 2) {      // N even
            const float* xr0 = x + (size_t)n * IN_F;
            const float* xr1 = xr0 + IN_F;
            float a0 = 0.f, a1 = 0.f;
            #pragma unroll
            for (int k = 0; k < IN_F; ++k) {
                a0 += xr0[k] * w[k];
                a1 += xr1[k] * w[k];
            }
            xwb[coff + (size_t)n * CH_F]       = f2bf(a0);
            xwb[coff + (size_t)(n + 1) * CH_F] = f2bf(a1);
        }
        return;
    }

    // ---- bucket1 branch ----
    for (int b = t; b < BUCKETS; b += 512) { histE[b] = 0; histN[b] = 0; }
    __syncthreads();
    int p0 = blockIdx.x * CHUNK_P;
    int nv[B1_NIT], ev[B1_NIT];
    #pragma unroll
    for (int r = 0; r < B1_NIT; ++r) {
        int i = t + (r << 9);
        if (i < CHUNK_P) {
            nv[r] = ni[p0 + i];
            ev[r] = ei[p0 + i];
            atomicAdd(&histE[ev[r] >> BSHIFT], 1);
            atomicAdd(&histN[nv[r] >> BSHIFT], 1);
        }
    }
    __syncthreads();
    // scan edge-side (wave shfl scan + 8-wave combine)
    {
        int c = (t < BUCKETS) ? histE[t] : 0;
        int incl = wave_incl_scan(c, lane);
        if (lane == 63) wsum[wv] = incl;
        __syncthreads();
        if (wv == 0 && lane < 8) {
            int x_ = wsum[lane];
            int xi = x_;
            #pragma unroll
            for (int off = 1; off < 8; off <<= 1) {
                int u = __shfl_up(xi, off, 8);
                if (lane >= off) xi += u;
            }
            wexc[lane] = xi - x_;          // exclusive across waves
        }
        __syncthreads();
        incl += wexc[wv];
        if (t < BUCKETS) {
            gbE[t] = (c > 0) ? atomicAdd(&curE[t], c) : 0;
            cE[t] = incl - c;              // exclusive local cursor
        }
    }
    __syncthreads();
    // scan node-side
    {
        int c = (t < BUCKETS) ? histN[t] : 0;
        int incl = wave_incl_scan(c, lane);
        if (lane == 63) wsum[wv] = incl;
        __syncthreads();
        if (wv == 0 && lane < 8) {
            int x_ = wsum[lane];
            int xi = x_;
            #pragma unroll
            for (int off = 1; off < 8; off <<= 1) {
                int u = __shfl_up(xi, off, 8);
                if (lane >= off) xi += u;
            }
            wexc[lane] = xi - x_;
        }
        __syncthreads();
        incl += wexc[wv];
        if (t < BUCKETS) {
            gbN[t] = (c > 0) ? atomicAdd(&curN[t], c) : 0;
            cN[t] = incl - c;
        }
    }
    __syncthreads();
    // pass 2: place packed entries at sorted LDS positions (from registers)
    #pragma unroll
    for (int r = 0; r < B1_NIT; ++r) {
        int i = t + (r << 9);
        if (i < CHUNK_P) {
            int n = nv[r];
            int e = ev[r];
            int pE = atomicAdd(&cE[e >> BSHIFT], 1);
            scrE[pE] = ((unsigned)(e & 255) << 17) | (unsigned)n;
            int pN = atomicAdd(&cN[n >> BSHIFT], 1);
            scrN[pN] = ((unsigned)(n & 255) << 17) | (unsigned)e;
        }
    }
    __syncthreads();
    // flush: 32 groups x 16 lanes stream whole bucket runs (full-line bursts)
    int grp = t >> 4, l16 = t & 15;
    for (int b = grp; b < BUCKETS; b += 32) {
        int c = histE[b];
        if (c > 0) {
            int ls = cE[b] - c;            // cE[b] is inclusive end now
            int gs = gbE[b];
            size_t sb = (size_t)b * CAP;
            for (int j = l16; j < c; j += 16)
                if (gs + j < CAP) stageE[sb + gs + j] = scrE[ls + j];
        }
        c = histN[b];
        if (c > 0) {
            int ls = cN[b] - c;
            int gs = gbN[b];
            size_t sb = (size_t)b * CAP;
            for (int j = l16; j < c; j += 16)
                if (gs + j < CAP) stageN[sb + gs + j] = scrN[ls + j];
        }
    }
}

// ---------------------------------------------------------------------------
// K4: bucket phase 2 — E and N merged (782 blocks). Inlined base (sum of
// cur[0..b)). Counting-sort into LDS scratch, then LINEAR COALESCED flush
// adj[sbase+i] = scr[i]  (fixed R6's 5.6x write amplification).
// ---------------------------------------------------------------------------
__global__ __launch_bounds__(512) void k_bucket2(
    const unsigned int* __restrict__ stageE, const unsigned int* __restrict__ stageN,
    const int* __restrict__ curE, const int* __restrict__ curN,
    int* __restrict__ adjE, int* __restrict__ adjN,
    int* __restrict__ offE, int* __restrict__ offN,
    int* __restrict__ lenE, int* __restrict__ lenN)
{
    __shared__ int cnt[256];
    __shared__ int pos[256];               // per-key placement cursor
    __shared__ int wsum[8], wexc[8];
    __shared__ int sbase;
    __shared__ int scr[CAP];               // sorted values (36 KB)
    int bb = blockIdx.x;
    int side = (bb >= BUCKETS);
    int b = side ? bb - BUCKETS : bb;
    const unsigned int* stage = side ? stageN : stageE;
    const int* cur = side ? curN : curE;
    int* adj  = side ? adjN : adjE;
    int* offK = side ? offN : offE;
    int* lenK = side ? lenN : lenE;

    int t = threadIdx.x;
    int lane = t & 63;
    int wv = t >> 6;
    if (t == 0) sbase = 0;
    if (t < 8) { wsum[t] = 0; wexc[t] = 0; }
    if (t < 256) cnt[t] = 0;
    __syncthreads();
    // base = sum cur[0..b) (L2-warm, <=391 ints)
    int partial = 0;
    for (int i = t; i < b; i += 512) partial += cur[i];
    #pragma unroll
    for (int m = 1; m < 64; m <<= 1) partial += __shfl_xor(partial, m, 64);
    if (lane == 0 && partial != 0) atomicAdd(&sbase, partial);
    // per-key histogram
    int m_ = cur[b]; if (m_ > CAP) m_ = CAP;
    size_t sg = (size_t)b * CAP;
    for (int i = t; i < m_; i += 512)
        atomicAdd(&cnt[stage[sg + i] >> 17], 1);
    __syncthreads();
    // 256-entry exclusive scan of cnt: 4 wave scans + combine
    {
        int c = (t < 256) ? cnt[t] : 0;
        int incl = 0;
        if (t < 256) {
            incl = wave_incl_scan(c, lane);
            if (lane == 63) wsum[wv] = incl;
        }
        __syncthreads();
        if (wv == 0 && lane < 8) {
            int x_ = wsum[lane];
            int xi = x_;
            #pragma unroll
            for (int off = 1; off < 8; off <<= 1) {
                int u = __shfl_up(xi, off, 8);
                if (lane >= off) xi += u;
            }
            wexc[lane] = xi - x_;
        }
        __syncthreads();
        if (t < 256) {
            int loff = incl + wexc[wv] - c;   // local offset within bucket
            int k = (b << BSHIFT) + t;
            if (k < N_NODES) { offK[k] = sbase + loff; lenK[k] = c; }
            pos[t] = loff;
        }
    }
    __syncthreads();
    // place into LDS scratch (sorted by key)
    for (int i = t; i < m_; i += 512) {
        unsigned v = stage[sg + i];
        int p = atomicAdd(&pos[v >> 17], 1);
        scr[p] = (int)(v & 0x1FFFF);
    }
    __syncthreads();
    // flush: fully coalesced linear stream (full-line writes)
    for (int i = t; i < m_; i += 512)
        adj[sbase + i] = scr[i];
}

// ---------------------------------------------------------------------------
// gather-accumulate over adj[s,e) with 4 independent chains
// ---------------------------------------------------------------------------
__device__ __forceinline__ void gather_range(
    const int* __restrict__ adj, const unsigned short* __restrict__ tin,
    int s, int e, int sub, int cg, float acc[8])
{
    int i = s + sub;
    for (; i + 12 < e; i += 16) {
        int i0 = __builtin_nontemporal_load(&adj[i]);
        int i1 = __builtin_nontemporal_load(&adj[i + 4]);
        int i2 = __builtin_nontemporal_load(&adj[i + 8]);
        int i3 = __builtin_nontemporal_load(&adj[i + 12]);
        u16x8 v0 = *(const u16x8*)(tin + (size_t)i0 * CH_F + cg * 8);
        u16x8 v1 = *(const u16x8*)(tin + (size_t)i1 * CH_F + cg * 8);
        u16x8 v2 = *(const u16x8*)(tin + (size_t)i2 * CH_F + cg * 8);
        u16x8 v3 = *(const u16x8*)(tin + (size_t)i3 * CH_F + cg * 8);
        #pragma unroll
        for (int j = 0; j < 8; ++j) acc[j] += bf2f(v0[j]);
        #pragma unroll
        for (int j = 0; j < 8; ++j) acc[j] += bf2f(v1[j]);
        #pragma unroll
        for (int j = 0; j < 8; ++j) acc[j] += bf2f(v2[j]);
        #pragma unroll
        for (int j = 0; j < 8; ++j) acc[j] += bf2f(v3[j]);
    }
    if (i + 4 < e) {
        int i0 = __builtin_nontemporal_load(&adj[i]);
        int i1 = __builtin_nontemporal_load(&adj[i + 4]);
        u16x8 v0 = *(const u16x8*)(tin + (size_t)i0 * CH_F + cg * 8);
        u16x8 v1 = *(const u16x8*)(tin + (size_t)i1 * CH_F + cg * 8);
        #pragma unroll
        for (int j = 0; j < 8; ++j) acc[j] += bf2f(v0[j]);
        #pragma unroll
        for (int j = 0; j < 8; ++j) acc[j] += bf2f(v1[j]);
        i += 8;
    }
    if (i < e) {
        int i0 = __builtin_nontemporal_load(&adj[i]);
        u16x8 v0 = *(const u16x8*)(tin + (size_t)i0 * CH_F + cg * 8);
        #pragma unroll
        for (int j = 0; j < 8; ++j) acc[j] += bf2f(v0[j]);
    }
}

// ---------------------------------------------------------------------------
// K5: fused hop (R4 form — measured-best; residency splits all lost).
// 64 B rows = one cache line per gather. chunk = b & 1 (XCD parity).
// ---------------------------------------------------------------------------
__global__ __launch_bounds__(256) void k_hop(
    const int* __restrict__ adj, const int* __restrict__ offK,
    const int* __restrict__ lenK, const unsigned short* __restrict__ tin_base,
    unsigned short* __restrict__ tout_base, const float* __restrict__ bcc)
{
    int b = blockIdx.x;                    // grid = 12500
    int chunk = b & 1;
    int sb = b >> 1;                       // 0..6249
    const unsigned short* tin = tin_base + (size_t)chunk * (N_NODES * CH_F);
    unsigned short* tout = tout_base + (size_t)chunk * (N_NODES * CH_F);

    int lane = threadIdx.x & 63;
    int wv = threadIdx.x >> 6;
    int es  = lane >> 4;                   // segment within wave
    int sub = (lane >> 2) & 3;             // row-slot within segment
    int cg  = lane & 3;                    // 16 B quarter within 64 B row
    int k = (sb * 4 + wv) * 4 + es;
    int len = lenK[k];
    int start = offK[k];

    float acc[8];
    #pragma unroll
    for (int j = 0; j < 8; ++j) acc[j] = 0.f;

    gather_range(adj, tin, start, start + len, sub, cg, acc);

    #pragma unroll
    for (int m = 4; m < 16; m <<= 1) {     // reduce over sub (lane bits 2..3)
        #pragma unroll
        for (int j = 0; j < 8; ++j) acc[j] += __shfl_xor(acc[j], m, 64);
    }
    if ((lane & 12) == 0) {                // sub == 0
        float sc = (len > 0) ? 1.f / (float)len : 0.f;
        u16x8 o;
        if (bcc) {
            #pragma unroll
            for (int j = 0; j < 8; ++j)
                o[j] = f2bf(acc[j] * sc + bcc[chunk * CH_F + cg * 8 + j]);
        } else {
            #pragma unroll
            for (int j = 0; j < 8; ++j) o[j] = f2bf(acc[j] * sc);
        }
        __builtin_nontemporal_store(o, (u16x8*)(tout + (size_t)k * CH_F + cg * 8));
    }
}

// ---------------------------------------------------------------------------
// K6: MLP via MFMA: h = cv @ Wm + bm -> BF16 scratch hb (half the h-traffic
// of f32-in-out; R8's grid-barrier fusion spun 120 µs — reverted).
// BN partials block-reduced in LDS -> bns global atomics. 520 blocks.
// ---------------------------------------------------------------------------
__global__ __launch_bounds__(256) void k_mlp_mfma(
    const unsigned short* __restrict__ cvb, const float* __restrict__ Wm,
    const float* __restrict__ bm, unsigned short* __restrict__ hb,
    float* __restrict__ bns)
{
    __shared__ float red[128];             // [sum 64][sumsq 64]
    if (threadIdx.x < 128) red[threadIdx.x] = 0.f;
    __syncthreads();

    int lane = threadIdx.x & 63;
    int q = lane >> 4;
    int c = lane & 15;

    bf16x8 bf[4][2];
    #pragma unroll
    for (int t = 0; t < 4; ++t)
        #pragma unroll
        for (int kh = 0; kh < 2; ++kh)
            #pragma unroll
            for (int j = 0; j < 8; ++j)
                bf[t][kh][j] = (short)f2bf(Wm[(kh * 32 + q * 8 + j) * OUT_F + t * 16 + c]);
    float bmv[4];
    #pragma unroll
    for (int t = 0; t < 4; ++t) bmv[t] = bm[t * 16 + c];

    float s[4], s2[4];
    #pragma unroll
    for (int t = 0; t < 4; ++t) { s[t] = 0.f; s2[t] = 0.f; }

    int gw = (blockIdx.x * 256 + threadIdx.x) >> 6;
    int nw = gridDim.x * 4;
    const int NT = N_NODES / 16;
    for (int tile = gw; tile < NT; tile += nw) {
        int r0 = tile * 16;
        size_t rowoff = (size_t)(r0 + c) * CH_F + q * 8;
        bf16x8 a0 = *(const bf16x8*)(cvb + rowoff);
        bf16x8 a1 = *(const bf16x8*)(cvb + (size_t)(N_NODES * CH_F) + rowoff);
        #pragma unroll
        for (int t = 0; t < 4; ++t) {
            f32x4 acc = {0.f, 0.f, 0.f, 0.f};
            acc = __builtin_amdgcn_mfma_f32_16x16x32_bf16(a0, bf[t][0], acc, 0, 0, 0);
            acc = __builtin_amdgcn_mfma_f32_16x16x32_bf16(a1, bf[t][1], acc, 0, 0, 0);
            #pragma unroll
            for (int r = 0; r < 4; ++r) {
                float hv = acc[r] + bmv[t];
                hb[(size_t)(r0 + q * 4 + r) * OUT_F + t * 16 + c] = f2bf(hv);
                s[t]  += hv;
                s2[t] += hv * hv;
            }
        }
    }
    #pragma unroll
    for (int t = 0; t < 4; ++t) {
        #pragma unroll
        for (int m = 16; m < 64; m <<= 1) {
            s[t]  += __shfl_xor(s[t],  m, 64);
            s2[t] += __shfl_xor(s2[t], m, 64);
        }
    }
    if (lane < 16) {
        #pragma unroll
        for (int t = 0; t < 4; ++t) {
            atomicAdd(&red[t * 16 + lane], s[t]);
            atomicAdd(&red[64 + t * 16 + lane], s2[t]);
        }
    }
    __syncthreads();
    if (threadIdx.x < 128) atomicAdd(&bns[threadIdx.x], red[threadIdx.x]);
}

// ---------------------------------------------------------------------------
// K7: BN normalize + LeakyReLU + residual + LeakyReLU. Reads bf16 hb,
// writes out once (no in-place RMW). 1024 blocks (4 waves/SIMD).
// ---------------------------------------------------------------------------
__global__ __launch_bounds__(256) void k_final(
    const float* __restrict__ x, const float* __restrict__ Wr,
    const float* __restrict__ br, const float* __restrict__ bns,
    const float* __restrict__ gamma, const float* __restrict__ beta,
    const unsigned short* __restrict__ hb, float* __restrict__ out)
{
    int lane = threadIdx.x & 63;
    float w[IN_F];
    #pragma unroll
    for (int k = 0; k < IN_F; ++k) w[k] = Wr[k * OUT_F + lane];
    const float inv_n = 1.f / (float)N_NODES;
    float mean = bns[lane] * inv_n;
    float var  = bns[64 + lane] * inv_n - mean * mean;
    float rstd = rsqrtf(var + BN_EPS);
    float g = gamma[lane], bt = beta[lane];
    float rb = br[lane];

    int gw = (blockIdx.x * 256 + threadIdx.x) >> 6;
    int nw = gridDim.x * 4;
    for (int n = gw * 2; n < N_NODES; n += nw * 2) {
        const float* xr0 = x + (size_t)n * IN_F;
        const float* xr1 = xr0 + IN_F;
        float r0 = rb, r1 = rb;
        #pragma unroll
        for (int k = 0; k < IN_F; ++k) {
            r0 += xr0[k] * w[k];
            r1 += xr1[k] * w[k];
        }
        float hv0 = bf2f(hb[(size_t)n * OUT_F + lane]);
        float hv1 = bf2f(hb[(size_t)(n + 1) * OUT_F + lane]);
        float a0 = g * (hv0 - mean) * rstd + bt;
        float a1 = g * (hv1 - mean) * rstd + bt;
        a0 = (a0 >= 0.f) ? a0 : SLOPE * a0;
        a1 = (a1 >= 0.f) ? a1 : SLOPE * a1;
        float y0 = a0 + r0;
        float y1 = a1 + r1;
        out[(size_t)n * OUT_F + lane]       = (y0 >= 0.f) ? y0 : SLOPE * y0;
        out[(size_t)(n + 1) * OUT_F + lane] = (y1 >= 0.f) ? y1 : SLOPE * y1;
    }
}

// ---------------------------------------------------------------------------
extern "C" void kernel_launch(void* const* d_in, const int* in_sizes, int n_in,
                              void* d_out, int out_size, void* d_ws, size_t ws_size,
                              hipStream_t stream) {
    const float* x     = (const float*)d_in[0];
    const int*   hidx  = (const int*)d_in[1];
    const int*   ni    = hidx;               // row 0: node idx
    const int*   ei    = hidx + P_PAIRS;     // row 1: edge idx
    const float* Wc    = (const float*)d_in[2];
    const float* bc    = (const float*)d_in[3];
    const float* Wm    = (const float*)d_in[4];
    const float* bm    = (const float*)d_in[5];
    const float* gamma = (const float*)d_in[6];
    const float* beta  = (const float*)d_in[7];
    const float* Wr    = (const float*)d_in[8];
    const float* br    = (const float*)d_in[9];
    float* out = (float*)d_out;

    // --- ws (~107 MB of the 256 MB workspace), no aliasing:
    int* adjE = (int*)d_ws;                                  // P
    int* adjN = adjE + P_PAIRS;                              // P
    unsigned int* stageE = (unsigned int*)(adjN + P_PAIRS);  // BUCKETS*CAP
    unsigned int* stageN = stageE + (size_t)BUCKETS * CAP;   // BUCKETS*CAP
    unsigned short* xwb = (unsigned short*)(stageN + (size_t)BUCKETS * CAP); // [2][N][32]
    unsigned short* efb = xwb + (size_t)NCH * N_NODES * CH_F;
    unsigned short* cvb = efb + (size_t)NCH * N_NODES * CH_F;
    unsigned short* hb  = cvb + (size_t)NCH * N_NODES * CH_F; // [N][64] bf16
    float* bns = (float*)(hb + (size_t)N_NODES * OUT_F);      // 128 f
    int* curE  = (int*)(bns + 128);
    int* curN  = curE + BUCKETS;
    int* offE  = curN + BUCKETS;
    int* lenE  = offE + N_NODES;
    int* offN  = lenE + N_NODES;
    int* lenN  = offN + N_NODES;

    // zero bns + curE + curN (contiguous)
    hipMemsetAsync(bns, 0, (128 + 2 * BUCKETS) * sizeof(int), stream);

    // bucket1 (blocks 0-499) + input GEMM (blocks 500-999) in one launch
    k_b1_gemm<<<B1_BLOCKS + K1_BLOCKS, 512, 0, stream>>>(
        ni, ei, curE, curN, stageE, stageN, x, Wc, xwb);

    k_bucket2<<<2 * BUCKETS, 512, 0, stream>>>(stageE, stageN, curE, curN,
                                               adjE, adjN, offE, offN,
                                               lenE, lenN);

    k_hop<<<12500, 256, 0, stream>>>(adjE, offE, lenE, xwb, efb, (const float*)nullptr);
    k_hop<<<12500, 256, 0, stream>>>(adjN, offN, lenN, efb, cvb, bc);

    k_mlp_mfma<<<520, 256, 0, stream>>>(cvb, Wm, bm, hb, bns);
    k_final<<<1024, 256, 0, stream>>>(x, Wr, br, bns, gamma, beta, hb, out);
}